// Round 4
// baseline (2628.348 us; speedup 1.0000x reference)
//
#include <hip/hip_runtime.h>
#include <math.h>

#define BATCH 32768
#define NVARS 50
#define H1 1024
#define H2 1024
#define H3 256
#define NOUT 100
#define EPSBN 1e-5f

#define TF   0.05f
#define AF   20.0f
#define JF   400.0f
#define VMAX 1.0f
#define AMAX 2.0f
#define JMAX 5.0f
#define PMAX 3.14159265358979323846f

typedef unsigned short ushort_t;
typedef __attribute__((ext_vector_type(8))) short short8;
typedef __attribute__((ext_vector_type(4))) float f32x4;

// ---------------------------------------------------------------------------
// Device-global scratch (no ws_size dependence).
// ---------------------------------------------------------------------------
__device__ float g_z1[(size_t)BATCH * H1];   // z1 / (z3, nno reuse)
__device__ float g_z2[(size_t)BATCH * H2];
__device__ float g_ps[32 * 1024];
__device__ float g_pq[32 * 1024];
__device__ float g_scale[3 * 1024];
__device__ float g_shift[3 * 1024];
__device__ float g_Mi[2500];
__device__ float g_xT[(size_t)NVARS * BATCH];   // x transposed [50][BATCH]
__device__ float g_nnT[(size_t)NOUT * BATCH];   // nn out transposed [100][BATCH]
__device__ ushort_t g_w2h[(size_t)H1 * H2], g_w2m[(size_t)H1 * H2], g_w2l[(size_t)H1 * H2];
__device__ ushort_t g_w3h[(size_t)H2 * H3], g_w3m[(size_t)H2 * H3], g_w3l[(size_t)H2 * H3];

// ---------------------------------------------------------------------------
// float -> bf16 triple split (RNE), f ~= hi + mid + lo with rel err ~2^-26.
// ---------------------------------------------------------------------------
__device__ __forceinline__ void split3(float f, ushort_t& h, ushort_t& m, ushort_t& l)
{
    unsigned u = __float_as_uint(f);
    unsigned r = u + 0x7fffu + ((u >> 16) & 1u);
    h = (ushort_t)(r >> 16);
    float f1 = f - __uint_as_float((unsigned)h << 16);
    unsigned u1 = __float_as_uint(f1);
    unsigned r1 = u1 + 0x7fffu + ((u1 >> 16) & 1u);
    m = (ushort_t)(r1 >> 16);
    float f2 = f1 - __uint_as_float((unsigned)m << 16);
    unsigned u2 = __float_as_uint(f2);
    unsigned r2 = u2 + 0x7fffu + ((u2 >> 16) & 1u);
    l = (ushort_t)(r2 >> 16);
}

// ---------------------------------------------------------------------------
// Build MiT[k*50+j] = Q_inv[j][k] (transposed) via f64 Gauss-Jordan w/ pivot.
// ---------------------------------------------------------------------------
__global__ void build_M(float* __restrict__ Mout)
{
    __shared__ double aug[52][104];
    __shared__ int piv;
    int tid = threadIdx.x;

    const double Tf = (double)0.05f;
    const double c3[3] = { 400.0, -800.0, 400.0 };

    for (int idx = tid; idx < 52 * 104; idx += 64) {
        int j = idx / 104, k = idx % 104;
        double v = 0.0;
        if (k >= 52) {
            v = (k == 52 + j) ? 1.0 : 0.0;
        } else if (j < 50 && k < 50) {
            double q = (j == k) ? 3.0 : 0.0;
            if (j == k) q += 800.0 * ((j < 49 ? 1 : 0) + (j > 0 ? 1 : 0));
            if (j - k == 1 || k - j == 1) q += -800.0;
            int lo = j > k ? j : k; lo -= 2; if (lo < 0) lo = 0;
            int hi = j < k ? j : k; if (hi > 47) hi = 47;
            for (int i = lo; i <= hi; ++i) {
                int dj = j - i, dk = k - i;
                if (dj >= 0 && dj <= 2 && dk >= 0 && dk <= 2)
                    q += 2.0 * c3[dj] * c3[dk];
            }
            int mx = j > k ? j : k;
            q += 2.0 * Tf * Tf * (double)(50 - mx);
            v = q;
        } else if ((j == 50 && k == 0) || (j == 0 && k == 50) ||
                   (j == 51 && k == 49) || (j == 49 && k == 51)) {
            v = 1.0;
        }
        aug[j][k] = v;
    }
    __syncthreads();

    for (int c = 0; c < 52; ++c) {
        if (tid == 0) {
            int p = c; double best = fabs(aug[c][c]);
            for (int r = c + 1; r < 52; ++r) {
                double v = fabs(aug[r][c]);
                if (v > best) { best = v; p = r; }
            }
            piv = p;
        }
        __syncthreads();
        int p = piv;
        if (p != c) {
            for (int k = tid; k < 104; k += 64) {
                double t = aug[c][k]; aug[c][k] = aug[p][k]; aug[p][k] = t;
            }
        }
        __syncthreads();
        double pv = aug[c][c];
        __syncthreads();
        for (int k = tid; k < 104; k += 64) aug[c][k] /= pv;
        __syncthreads();
        if (tid < 52 && tid != c) {
            double f = aug[tid][c];
            for (int k = 0; k < 104; ++k) aug[tid][k] -= f * aug[c][k];
        }
        __syncthreads();
    }

    // MiT[k][j] = Qinv[j][k]
    for (int idx = tid; idx < 2500; idx += 64) {
        int k = idx / 50, j = idx % 50;
        Mout[idx] = (float)aug[j][52 + k];
    }
}

// ---------------------------------------------------------------------------
// Transpose Z[BATCH][C] -> ZT[C][BATCH], 64 rows per block, coalesced both ways.
// ---------------------------------------------------------------------------
template <int C>
__global__ __launch_bounds__(64)
void transp(const float* __restrict__ Z, float* __restrict__ ZT)
{
    __shared__ float t[64][C + 1];
    const int lane = threadIdx.x;
    const size_t r0 = (size_t)blockIdx.x * 64;
#pragma unroll 1
    for (int i = 0; i < C; ++i) {
        int idx = i * 64 + lane;
        int r = idx / C, c = idx % C;
        t[r][c] = Z[r0 * C + idx];
    }
    __syncthreads();
#pragma unroll 1
    for (int c = 0; c < C; ++c)
        ZT[(size_t)c * BATCH + r0 + lane] = t[lane][c];
}

// ---------------------------------------------------------------------------
// Transpose + triple-split W[K][N] f32 -> Wt{h,m,l}[N][K] bf16.
// ---------------------------------------------------------------------------
__global__ __launch_bounds__(256)
void wsplit(const float* __restrict__ W, ushort_t* __restrict__ WH,
            ushort_t* __restrict__ WM, ushort_t* __restrict__ WL, int K, int N)
{
    __shared__ float tile[32][33];
    int t = threadIdx.x;
    int n0 = blockIdx.x * 32, k0 = blockIdx.y * 32;
    int rr = t >> 5, cc = t & 31;
#pragma unroll
    for (int i = 0; i < 4; ++i)
        tile[rr + i * 8][cc] = W[(size_t)(k0 + rr + i * 8) * N + n0 + cc];
    __syncthreads();
#pragma unroll
    for (int i = 0; i < 4; ++i) {
        int n = n0 + rr + i * 8, k = k0 + cc;
        float f = tile[cc][rr + i * 8];
        ushort_t h, m, l;
        split3(f, h, m, l);
        WH[(size_t)n * K + k] = h;
        WM[(size_t)n * K + k] = m;
        WL[(size_t)n * K + k] = l;
    }
}

// ---------------------------------------------------------------------------
// MFMA GEMM, fp32-emulated via bf16 triple split (6 MFMAs per frag pair).
// ---------------------------------------------------------------------------
template <int BN_APPLY>
__global__ __launch_bounds__(256)
void gemm_mfma(const float* __restrict__ A,
               const ushort_t* __restrict__ WH, const ushort_t* __restrict__ WM,
               const ushort_t* __restrict__ WL,
               const float* __restrict__ bias,
               const float* __restrict__ scale, const float* __restrict__ shift,
               float* __restrict__ C, int M, int K, int N)
{
    const int TIER = 128 * 80;
    __shared__ __attribute__((aligned(16))) unsigned char lds[6 * 128 * 80];
    char* Lb = (char*)lds;

    const int t = threadIdx.x;
    const int r = t >> 1, kh = t & 1;
    const int row0 = blockIdx.x * 128, col0 = blockIdx.y * 128;

    const float*    Ab  = A  + (size_t)(row0 + r) * K + kh * 16;
    const ushort_t* WHb = WH + (size_t)(col0 + r) * K + kh * 16;
    const ushort_t* WMb = WM + (size_t)(col0 + r) * K + kh * 16;
    const ushort_t* WLb = WL + (size_t)(col0 + r) * K + kh * 16;
    const int awb = r * 80 + kh * 32;

    const int lane = t & 63, w = t >> 6;
    const int wm = w >> 1, wn = w & 1;
    const int fr = lane & 15, fg = lane >> 4;
    const int aoff = (wm * 64 + fr) * 80 + fg * 16;
    const int boff = 3 * TIER + (wn * 64 + fr) * 80 + fg * 16;

    f32x4 acc[4][4];
#pragma unroll
    for (int m = 0; m < 4; ++m)
#pragma unroll
        for (int n = 0; n < 4; ++n)
#pragma unroll
            for (int q = 0; q < 4; ++q) acc[m][n][q] = 0.f;

    for (int k0 = 0; k0 < K; k0 += 32) {
        float4 f[4];
#pragma unroll
        for (int i = 0; i < 4; ++i) f[i] = *(const float4*)(Ab + k0 + i * 4);
        if (BN_APPLY) {
#pragma unroll
            for (int i = 0; i < 4; ++i) {
                float4 sc = *(const float4*)(scale + k0 + kh * 16 + i * 4);
                float4 sh = *(const float4*)(shift + k0 + kh * 16 + i * 4);
                f[i].x = fmaxf(f[i].x * sc.x + sh.x, 0.f);
                f[i].y = fmaxf(f[i].y * sc.y + sh.y, 0.f);
                f[i].z = fmaxf(f[i].z * sc.z + sh.z, 0.f);
                f[i].w = fmaxf(f[i].w * sc.w + sh.w, 0.f);
            }
        }
        ushort_t hh[16], mm[16], ll[16];
#pragma unroll
        for (int i = 0; i < 4; ++i) {
            split3(f[i].x, hh[i*4+0], mm[i*4+0], ll[i*4+0]);
            split3(f[i].y, hh[i*4+1], mm[i*4+1], ll[i*4+1]);
            split3(f[i].z, hh[i*4+2], mm[i*4+2], ll[i*4+2]);
            split3(f[i].w, hh[i*4+3], mm[i*4+3], ll[i*4+3]);
        }
#define PK(a,b) (((unsigned)(a)) | (((unsigned)(b)) << 16))
        *(uint4*)(Lb + awb)              = make_uint4(PK(hh[0],hh[1]), PK(hh[2],hh[3]), PK(hh[4],hh[5]), PK(hh[6],hh[7]));
        *(uint4*)(Lb + awb + 16)         = make_uint4(PK(hh[8],hh[9]), PK(hh[10],hh[11]), PK(hh[12],hh[13]), PK(hh[14],hh[15]));
        *(uint4*)(Lb + TIER + awb)       = make_uint4(PK(mm[0],mm[1]), PK(mm[2],mm[3]), PK(mm[4],mm[5]), PK(mm[6],mm[7]));
        *(uint4*)(Lb + TIER + awb + 16)  = make_uint4(PK(mm[8],mm[9]), PK(mm[10],mm[11]), PK(mm[12],mm[13]), PK(mm[14],mm[15]));
        *(uint4*)(Lb + 2*TIER + awb)     = make_uint4(PK(ll[0],ll[1]), PK(ll[2],ll[3]), PK(ll[4],ll[5]), PK(ll[6],ll[7]));
        *(uint4*)(Lb + 2*TIER + awb + 16)= make_uint4(PK(ll[8],ll[9]), PK(ll[10],ll[11]), PK(ll[12],ll[13]), PK(ll[14],ll[15]));
#undef PK
        {
            const uint4* p0 = (const uint4*)(WHb + k0);
            const uint4* p1 = (const uint4*)(WMb + k0);
            const uint4* p2 = (const uint4*)(WLb + k0);
            *(uint4*)(Lb + 3*TIER + awb)      = p0[0];
            *(uint4*)(Lb + 3*TIER + awb + 16) = p0[1];
            *(uint4*)(Lb + 4*TIER + awb)      = p1[0];
            *(uint4*)(Lb + 4*TIER + awb + 16) = p1[1];
            *(uint4*)(Lb + 5*TIER + awb)      = p2[0];
            *(uint4*)(Lb + 5*TIER + awb + 16) = p2[1];
        }
        __syncthreads();

        short8 ah[4], am4[4], al4[4], bh[4], bm4[4], bl4[4];
#pragma unroll
        for (int m = 0; m < 4; ++m) {
            ah[m]  = *(short8*)(Lb + aoff + m * 1280);
            am4[m] = *(short8*)(Lb + TIER + aoff + m * 1280);
            al4[m] = *(short8*)(Lb + 2 * TIER + aoff + m * 1280);
        }
#pragma unroll
        for (int n = 0; n < 4; ++n) {
            bh[n]  = *(short8*)(Lb + boff + n * 1280);
            bm4[n] = *(short8*)(Lb + TIER + boff + n * 1280);
            bl4[n] = *(short8*)(Lb + 2 * TIER + boff + n * 1280);
        }
#pragma unroll
        for (int m = 0; m < 4; ++m)
#pragma unroll
            for (int n = 0; n < 4; ++n) {
                f32x4 c = acc[m][n];
                c = __builtin_amdgcn_mfma_f32_16x16x32_bf16(al4[m], bh[n],  c, 0, 0, 0);
                c = __builtin_amdgcn_mfma_f32_16x16x32_bf16(ah[m],  bl4[n], c, 0, 0, 0);
                c = __builtin_amdgcn_mfma_f32_16x16x32_bf16(am4[m], bm4[n], c, 0, 0, 0);
                c = __builtin_amdgcn_mfma_f32_16x16x32_bf16(am4[m], bh[n],  c, 0, 0, 0);
                c = __builtin_amdgcn_mfma_f32_16x16x32_bf16(ah[m],  bm4[n], c, 0, 0, 0);
                c = __builtin_amdgcn_mfma_f32_16x16x32_bf16(ah[m],  bh[n],  c, 0, 0, 0);
                acc[m][n] = c;
            }
        __syncthreads();
    }

#pragma unroll
    for (int m = 0; m < 4; ++m)
#pragma unroll
        for (int n = 0; n < 4; ++n) {
            int cc = col0 + wn * 64 + n * 16 + fr;
            float b = bias[cc];
#pragma unroll
            for (int q = 0; q < 4; ++q) {
                int rr = row0 + wm * 64 + m * 16 + fg * 4 + q;
                C[(size_t)rr * N + cc] = acc[m][n][q] + b;
            }
        }
}

// ---------------------------------------------------------------------------
// fp32 tiled GEMM (GEMM1 K=50, GEMM4 N=100).
// ---------------------------------------------------------------------------
template <int BN_APPLY>
__global__ __launch_bounds__(256)
void gemm_k(const float* __restrict__ A, const float* __restrict__ W,
            const float* __restrict__ bias,
            const float* __restrict__ scale, const float* __restrict__ shift,
            float* __restrict__ C, int M, int K, int N)
{
    const int BM = 128, BN = 128, BK = 16;
    __shared__ __attribute__((aligned(16))) float As[BK][BM + 4];
    __shared__ __attribute__((aligned(16))) float Ws[BK][BN];
    int tid = threadIdx.x;
    int tm = tid >> 4, tn = tid & 15;
    int row0 = blockIdx.x * BM, col0 = blockIdx.y * BN;

    float acc[8][8];
#pragma unroll
    for (int i = 0; i < 8; ++i)
#pragma unroll
        for (int j = 0; j < 8; ++j) acc[i][j] = 0.f;

    int alr = tid >> 4;
    int alk = tid & 15;
    int wlc = tid & 127;
    int wlk = tid >> 7;

    for (int k0 = 0; k0 < K; k0 += BK) {
#pragma unroll
        for (int i = 0; i < 8; ++i) {
            int rr = row0 + alr + i * 16;
            int kk = k0 + alk;
            float v = 0.f;
            if (kk < K) {
                v = A[(size_t)rr * K + kk];
                if (BN_APPLY) v = fmaxf(v * scale[kk] + shift[kk], 0.f);
            }
            As[alk][alr + i * 16] = v;
        }
#pragma unroll
        for (int i = 0; i < 8; ++i) {
            int kk = k0 + wlk + i * 2;
            int cc = col0 + wlc;
            Ws[wlk + i * 2][wlc] = (kk < K && cc < N) ? W[(size_t)kk * N + cc] : 0.f;
        }
        __syncthreads();
#pragma unroll
        for (int kk = 0; kk < BK; ++kk) {
            float av[8], wv[8];
            float4 tv;
            tv = *(const float4*)&As[kk][tm * 8];     av[0]=tv.x; av[1]=tv.y; av[2]=tv.z; av[3]=tv.w;
            tv = *(const float4*)&As[kk][tm * 8 + 4]; av[4]=tv.x; av[5]=tv.y; av[6]=tv.z; av[7]=tv.w;
            tv = *(const float4*)&Ws[kk][tn * 8];     wv[0]=tv.x; wv[1]=tv.y; wv[2]=tv.z; wv[3]=tv.w;
            tv = *(const float4*)&Ws[kk][tn * 8 + 4]; wv[4]=tv.x; wv[5]=tv.y; wv[6]=tv.z; wv[7]=tv.w;
#pragma unroll
            for (int i = 0; i < 8; ++i)
#pragma unroll
                for (int j = 0; j < 8; ++j) acc[i][j] += av[i] * wv[j];
        }
        __syncthreads();
    }
#pragma unroll
    for (int i = 0; i < 8; ++i) {
        int rr = row0 + tm * 8 + i;
#pragma unroll
        for (int j = 0; j < 8; ++j) {
            int cc = col0 + tn * 8 + j;
            if (cc < N) C[(size_t)rr * N + cc] = acc[i][j] + bias[cc];
        }
    }
}

// ---------------------------------------------------------------------------
// BatchNorm stats.
// ---------------------------------------------------------------------------
__global__ __launch_bounds__(256)
void stats_part(const float* __restrict__ Z, float* __restrict__ ps,
                float* __restrict__ pq, int M, int C, int chunks)
{
    int lc = threadIdx.x & 63;
    int col = blockIdx.x * 64 + lc;
    int rg = threadIdx.x >> 6;
    int rpc = M / chunks;
    int r0 = blockIdx.y * rpc;
    float s = 0.f, q = 0.f;
    for (int rr = r0 + rg; rr < r0 + rpc; rr += 4) {
        float v = Z[(size_t)rr * C + col];
        s += v; q += v * v;
    }
    __shared__ float ls[4][64], lq[4][64];
    ls[rg][lc] = s; lq[rg][lc] = q;
    __syncthreads();
    if (rg == 0) {
        float S = ls[0][lc] + ls[1][lc] + ls[2][lc] + ls[3][lc];
        float Q = lq[0][lc] + lq[1][lc] + lq[2][lc] + lq[3][lc];
        ps[(size_t)blockIdx.y * C + col] = S;
        pq[(size_t)blockIdx.y * C + col] = Q;
    }
}

__global__ void stats_fin(const float* __restrict__ ps, const float* __restrict__ pq,
                          const float* __restrict__ g, const float* __restrict__ be,
                          float* __restrict__ scale, float* __restrict__ shift,
                          int C, int M, int chunks)
{
    int c = blockIdx.x * blockDim.x + threadIdx.x;
    if (c >= C) return;
    float S = 0.f, Q = 0.f;
    for (int i = 0; i < chunks; ++i) { S += ps[(size_t)i * C + c]; Q += pq[(size_t)i * C + c]; }
    float inv = 1.0f / (float)M;
    float mean = S * inv;
    float var = Q * inv - mean * mean;
    float rstd = 1.0f / sqrtf(var + EPSBN);
    float sc = g[c] * rstd;
    scale[c] = sc;
    shift[c] = be[c] - mean * sc;
}

// ---------------------------------------------------------------------------
// Fused 15-iteration ADMM. All state in REGISTERS (fully-unrolled stencil
// passes, compile-time indices -> no scratch, no LDS latency in the serial
// chain). Matvec: rh staged in a small LDS strip (runtime-k read), xin[50]
// as 50 independent register accumulators -> dependency-free FMA stream.
// ---------------------------------------------------------------------------
__global__ __launch_bounds__(64, 1)
void iter_k(const float* __restrict__ XT, const float* __restrict__ NNT,
            const float* __restrict__ MiT, float* __restrict__ out)
{
    __shared__ float sRh[50 * 64];
    const int lane = threadIdx.x;
    const int row = blockIdx.x * 64 + lane;

    float xi[50], lam[50], xin[50], rh[50];
#pragma unroll
    for (int k = 0; k < 50; ++k) xi[k]  = NNT[(size_t)k * BATCH + row];
#pragma unroll
    for (int k = 0; k < 50; ++k) lam[k] = NNT[(size_t)(50 + k) * BATCH + row];

    float fps = 0.f, prs = 0.f;

#pragma unroll 1
    for (int it = 0; it < 15; ++it) {
        // ---- pass 1: rh = A^T min(b, A xi) (registers, unrolled)
#pragma unroll
        for (int k = 0; k < 50; ++k) rh[k] = 0.f;
        {
            float pre = 0.f, Sp = 0.f, ap = 0.f;
#pragma unroll
            for (int k = 0; k < 50; ++k) {
                rh[k] += fminf(VMAX, xi[k]) - fminf(VMAX, -xi[k]);
                rh[k] -= TF * Sp;
                pre += xi[k];
                float p = TF * pre;
                Sp += fminf(PMAX, p) - fminf(PMAX, -p);
                if (k < 49) {
                    float a = AF * (xi[k + 1] - xi[k]);
                    float da = fminf(AMAX, a) - fminf(AMAX, -a);
                    rh[k] -= AF * da; rh[k + 1] += AF * da;
                    if (k >= 1) {
                        float j = AF * (a - ap);
                        float dj = fminf(JMAX, j) - fminf(JMAX, -j);
                        rh[k - 1] += JF * dj; rh[k] -= 2.f * JF * dj; rh[k + 1] += JF * dj;
                    }
                    ap = a;
                }
            }
            float Stot = TF * Sp;
            // ---- combine -> LDS rh strip (x reloaded coalesced from XT)
#pragma unroll
            for (int k = 0; k < 50; ++k)
                sRh[(k << 6) + lane] = rh[k] + lam[k] + XT[(size_t)k * BATCH + row] + Stot;
        }
        __syncthreads();

        // ---- xin[j] = sum_k MiT[k][j] * rh[k]; 50 independent accumulators
#pragma unroll
        for (int j = 0; j < 50; ++j) xin[j] = 0.f;
#pragma unroll 2
        for (int k = 0; k < 50; ++k) {
            float rv = sRh[(k << 6) + lane];
#pragma unroll
            for (int j = 0; j < 50; ++j)
                xin[j] += MiT[k * 50 + j] * rv;
        }

        // ---- pass 2: residual/s norms + g (into rh regs), unrolled
        float res2 = 0.f, ds2 = 0.f, dxi2 = 0.f, dlam2 = 0.f;
#pragma unroll
        for (int k = 0; k < 50; ++k) rh[k] = 0.f;
        {
            float preo = 0.f, pren = 0.f, SpF = 0.f, aop = 0.f, anp = 0.f;
#pragma unroll
            for (int k = 0; k < 50; ++k) {
                float xoc = xi[k], xnc = xin[k];
                float d = xoc - xnc; dxi2 += d * d;
                float rp = fmaxf(xnc - VMAX, 0.f), rm = fmaxf(-xnc - VMAX, 0.f);
                res2 += rp * rp + rm * rm;
                float so = fmaxf(VMAX - xoc, 0.f), sn = fmaxf(VMAX - xnc, 0.f);
                d = so - sn; ds2 += d * d;
                so = fmaxf(VMAX + xoc, 0.f); sn = fmaxf(VMAX + xnc, 0.f);
                d = so - sn; ds2 += d * d;
                rh[k] += rp - rm;
                rh[k] -= TF * SpF;
                preo += xoc; pren += xnc;
                float po = TF * preo, pn = TF * pren;
                rp = fmaxf(pn - PMAX, 0.f); rm = fmaxf(-pn - PMAX, 0.f);
                res2 += rp * rp + rm * rm;
                so = fmaxf(PMAX - po, 0.f); sn = fmaxf(PMAX - pn, 0.f);
                d = so - sn; ds2 += d * d;
                so = fmaxf(PMAX + po, 0.f); sn = fmaxf(PMAX + pn, 0.f);
                d = so - sn; ds2 += d * d;
                SpF += rp - rm;
                if (k < 49) {
                    float ao = AF * (xi[k + 1] - xoc), an = AF * (xin[k + 1] - xnc);
                    rp = fmaxf(an - AMAX, 0.f); rm = fmaxf(-an - AMAX, 0.f);
                    res2 += rp * rp + rm * rm;
                    so = fmaxf(AMAX - ao, 0.f); sn = fmaxf(AMAX - an, 0.f);
                    d = so - sn; ds2 += d * d;
                    so = fmaxf(AMAX + ao, 0.f); sn = fmaxf(AMAX + an, 0.f);
                    d = so - sn; ds2 += d * d;
                    float fa = rp - rm; rh[k] -= AF * fa; rh[k + 1] += AF * fa;
                    if (k >= 1) {
                        float jo = AF * (ao - aop), jn = AF * (an - anp);
                        rp = fmaxf(jn - JMAX, 0.f); rm = fmaxf(-jn - JMAX, 0.f);
                        res2 += rp * rp + rm * rm;
                        so = fmaxf(JMAX - jo, 0.f); sn = fmaxf(JMAX - jn, 0.f);
                        d = so - sn; ds2 += d * d;
                        so = fmaxf(JMAX + jo, 0.f); sn = fmaxf(JMAX + jn, 0.f);
                        d = so - sn; ds2 += d * d;
                        float fj = rp - rm;
                        rh[k - 1] += JF * fj; rh[k] -= 2.f * JF * fj; rh[k + 1] += JF * fj;
                    }
                    aop = ao; anp = an;
                }
            }
            float SF = TF * SpF;
#pragma unroll
            for (int k = 0; k < 50; ++k) {
                float gk = rh[k] + SF;
                dlam2 += gk * gk;
                lam[k] -= gk;
            }
        }
        prs += sqrtf(res2);
        fps += sqrtf(dxi2) + sqrtf(dlam2) + sqrtf(ds2);
#pragma unroll
        for (int k = 0; k < 50; ++k) xi[k] = xin[k];
        __syncthreads();
    }
#pragma unroll
    for (int k = 0; k < 50; ++k) out[(size_t)row * 50 + k] = xi[k];
    out[(size_t)BATCH * 50 + row] = fps * (1.f / 15.f);
    out[(size_t)BATCH * 51 + row] = prs * (1.f / 15.f);
}

// ---------------------------------------------------------------------------
extern "C" void kernel_launch(void* const* d_in, const int* in_sizes, int n_in,
                              void* d_out, int out_size, void* d_ws, size_t ws_size,
                              hipStream_t stream)
{
    const float* x   = (const float*)d_in[0];
    const float* W1  = (const float*)d_in[1];
    const float* b1  = (const float*)d_in[2];
    const float* g1  = (const float*)d_in[3];
    const float* be1 = (const float*)d_in[4];
    const float* W2  = (const float*)d_in[5];
    const float* b2  = (const float*)d_in[6];
    const float* g2  = (const float*)d_in[7];
    const float* be2 = (const float*)d_in[8];
    const float* W3  = (const float*)d_in[9];
    const float* b3  = (const float*)d_in[10];
    const float* g3  = (const float*)d_in[11];
    const float* be3 = (const float*)d_in[12];
    const float* W4  = (const float*)d_in[13];
    const float* b4  = (const float*)d_in[14];

    float *z1, *z2, *ps, *pq, *scb, *shb, *Mi, *xT, *nnT;
    ushort_t *w2h, *w2m, *w2l, *w3h, *w3m, *w3l;
    hipGetSymbolAddress((void**)&z1,  HIP_SYMBOL(g_z1));
    hipGetSymbolAddress((void**)&z2,  HIP_SYMBOL(g_z2));
    hipGetSymbolAddress((void**)&ps,  HIP_SYMBOL(g_ps));
    hipGetSymbolAddress((void**)&pq,  HIP_SYMBOL(g_pq));
    hipGetSymbolAddress((void**)&scb, HIP_SYMBOL(g_scale));
    hipGetSymbolAddress((void**)&shb, HIP_SYMBOL(g_shift));
    hipGetSymbolAddress((void**)&Mi,  HIP_SYMBOL(g_Mi));
    hipGetSymbolAddress((void**)&xT,  HIP_SYMBOL(g_xT));
    hipGetSymbolAddress((void**)&nnT, HIP_SYMBOL(g_nnT));
    hipGetSymbolAddress((void**)&w2h, HIP_SYMBOL(g_w2h));
    hipGetSymbolAddress((void**)&w2m, HIP_SYMBOL(g_w2m));
    hipGetSymbolAddress((void**)&w2l, HIP_SYMBOL(g_w2l));
    hipGetSymbolAddress((void**)&w3h, HIP_SYMBOL(g_w3h));
    hipGetSymbolAddress((void**)&w3m, HIP_SYMBOL(g_w3m));
    hipGetSymbolAddress((void**)&w3l, HIP_SYMBOL(g_w3l));

    float* z3  = z1;                        // z1 dead after GEMM2
    float* nno = z1 + (size_t)BATCH * H3;   // after z3
    float* sc1 = scb;        float* sh1 = shb;
    float* sc2 = scb + 1024; float* sh2 = shb + 1024;
    float* sc3 = scb + 2048; float* sh3 = shb + 2048;

    dim3 blk(256);
    hipLaunchKernelGGL(build_M, dim3(1), dim3(64), 0, stream, Mi);
    hipLaunchKernelGGL(wsplit, dim3(H2 / 32, H1 / 32), blk, 0, stream, W2, w2h, w2m, w2l, H1, H2);
    hipLaunchKernelGGL(wsplit, dim3(H3 / 32, H2 / 32), blk, 0, stream, W3, w3h, w3m, w3l, H2, H3);
    hipLaunchKernelGGL((transp<50>), dim3(BATCH / 64), dim3(64), 0, stream, x, xT);

    // L1: z1 = x @ W1 + b1 (fp32 vector path, K=50)
    hipLaunchKernelGGL((gemm_k<0>), dim3(BATCH / 128, H1 / 128), blk, 0, stream,
                       x, W1, b1, (const float*)nullptr, (const float*)nullptr,
                       z1, BATCH, NVARS, H1);
    hipLaunchKernelGGL(stats_part, dim3(H1 / 64, 32), blk, 0, stream, z1, ps, pq, BATCH, H1, 32);
    hipLaunchKernelGGL(stats_fin, dim3(4), dim3(256), 0, stream, ps, pq, g1, be1, sc1, sh1, H1, BATCH, 32);
    // L2: z2 = relu(bn(z1)) @ W2 + b2 (MFMA split)
    hipLaunchKernelGGL((gemm_mfma<1>), dim3(BATCH / 128, H2 / 128), blk, 0, stream,
                       z1, w2h, w2m, w2l, b2, sc1, sh1, z2, BATCH, H1, H2);
    hipLaunchKernelGGL(stats_part, dim3(H2 / 64, 32), blk, 0, stream, z2, ps, pq, BATCH, H2, 32);
    hipLaunchKernelGGL(stats_fin, dim3(4), dim3(256), 0, stream, ps, pq, g2, be2, sc2, sh2, H2, BATCH, 32);
    // L3: z3 = relu(bn(z2)) @ W3 + b3 (MFMA split)
    hipLaunchKernelGGL((gemm_mfma<1>), dim3(BATCH / 128, H3 / 128), blk, 0, stream,
                       z2, w3h, w3m, w3l, b3, sc2, sh2, z3, BATCH, H2, H3);
    hipLaunchKernelGGL(stats_part, dim3(H3 / 64, 32), blk, 0, stream, z3, ps, pq, BATCH, H3, 32);
    hipLaunchKernelGGL(stats_fin, dim3(1), dim3(256), 0, stream, ps, pq, g3, be3, sc3, sh3, H3, BATCH, 32);
    // L4: nno = relu(bn(z3)) @ W4 + b4 (fp32 vector path, N=100)
    hipLaunchKernelGGL((gemm_k<1>), dim3(BATCH / 128, 1), blk, 0, stream,
                       z3, W4, b4, sc3, sh3, nno, BATCH, H3, NOUT);
    hipLaunchKernelGGL((transp<100>), dim3(BATCH / 64), dim3(64), 0, stream, nno, nnT);
    // fused ADMM iterations (register-resident)
    hipLaunchKernelGGL(iter_k, dim3(BATCH / 64), dim3(64), 0, stream,
                       xT, nnT, Mi, (float*)d_out);
}

// Round 5
// 2501.186 us; speedup vs baseline: 1.0508x; 1.0508x over previous
//
#include <hip/hip_runtime.h>
#include <math.h>

#define BATCH 32768
#define NVARS 50
#define H1 1024
#define H2 1024
#define H3 256
#define NOUT 100
#define EPSBN 1e-5f

#define TF   0.05f
#define AF   20.0f
#define JF   400.0f
#define VMAX 1.0f
#define AMAX 2.0f
#define JMAX 5.0f
#define PMAX 3.14159265358979323846f

typedef unsigned short ushort_t;
typedef __attribute__((ext_vector_type(8))) short short8;
typedef __attribute__((ext_vector_type(4))) float f32x4;

// ---------------------------------------------------------------------------
// Device-global scratch (no ws_size dependence).
// ---------------------------------------------------------------------------
__device__ float g_z1[(size_t)BATCH * H1];   // z1 / (z3, nno reuse)
__device__ float g_z2[(size_t)BATCH * H2];
__device__ float g_ps[32 * 1024];
__device__ float g_pq[32 * 1024];
__device__ float g_scale[3 * 1024];
__device__ float g_shift[3 * 1024];
__device__ float g_Mi[2500];
__device__ float g_xT[(size_t)NVARS * BATCH];   // x transposed [50][BATCH]
__device__ float g_nnT[(size_t)NOUT * BATCH];   // nn out transposed [100][BATCH]
__device__ ushort_t g_w2h[(size_t)H1 * H2], g_w2m[(size_t)H1 * H2], g_w2l[(size_t)H1 * H2];
__device__ ushort_t g_w3h[(size_t)H2 * H3], g_w3m[(size_t)H2 * H3], g_w3l[(size_t)H2 * H3];

// ---------------------------------------------------------------------------
// float -> bf16 triple split (RNE), f ~= hi + mid + lo with rel err ~2^-26.
// ---------------------------------------------------------------------------
__device__ __forceinline__ void split3(float f, ushort_t& h, ushort_t& m, ushort_t& l)
{
    unsigned u = __float_as_uint(f);
    unsigned r = u + 0x7fffu + ((u >> 16) & 1u);
    h = (ushort_t)(r >> 16);
    float f1 = f - __uint_as_float((unsigned)h << 16);
    unsigned u1 = __float_as_uint(f1);
    unsigned r1 = u1 + 0x7fffu + ((u1 >> 16) & 1u);
    m = (ushort_t)(r1 >> 16);
    float f2 = f1 - __uint_as_float((unsigned)m << 16);
    unsigned u2 = __float_as_uint(f2);
    unsigned r2 = u2 + 0x7fffu + ((u2 >> 16) & 1u);
    l = (ushort_t)(r2 >> 16);
}

// ---------------------------------------------------------------------------
// Build MiT[k*50+j] = Q_inv[j][k] (transposed) via f64 Gauss-Jordan w/ pivot.
// ---------------------------------------------------------------------------
__global__ void build_M(float* __restrict__ Mout)
{
    __shared__ double aug[52][104];
    __shared__ int piv;
    int tid = threadIdx.x;

    const double Tf = (double)0.05f;
    const double c3[3] = { 400.0, -800.0, 400.0 };

    for (int idx = tid; idx < 52 * 104; idx += 64) {
        int j = idx / 104, k = idx % 104;
        double v = 0.0;
        if (k >= 52) {
            v = (k == 52 + j) ? 1.0 : 0.0;
        } else if (j < 50 && k < 50) {
            double q = (j == k) ? 3.0 : 0.0;
            if (j == k) q += 800.0 * ((j < 49 ? 1 : 0) + (j > 0 ? 1 : 0));
            if (j - k == 1 || k - j == 1) q += -800.0;
            int lo = j > k ? j : k; lo -= 2; if (lo < 0) lo = 0;
            int hi = j < k ? j : k; if (hi > 47) hi = 47;
            for (int i = lo; i <= hi; ++i) {
                int dj = j - i, dk = k - i;
                if (dj >= 0 && dj <= 2 && dk >= 0 && dk <= 2)
                    q += 2.0 * c3[dj] * c3[dk];
            }
            int mx = j > k ? j : k;
            q += 2.0 * Tf * Tf * (double)(50 - mx);
            v = q;
        } else if ((j == 50 && k == 0) || (j == 0 && k == 50) ||
                   (j == 51 && k == 49) || (j == 49 && k == 51)) {
            v = 1.0;
        }
        aug[j][k] = v;
    }
    __syncthreads();

    for (int c = 0; c < 52; ++c) {
        if (tid == 0) {
            int p = c; double best = fabs(aug[c][c]);
            for (int r = c + 1; r < 52; ++r) {
                double v = fabs(aug[r][c]);
                if (v > best) { best = v; p = r; }
            }
            piv = p;
        }
        __syncthreads();
        int p = piv;
        if (p != c) {
            for (int k = tid; k < 104; k += 64) {
                double t = aug[c][k]; aug[c][k] = aug[p][k]; aug[p][k] = t;
            }
        }
        __syncthreads();
        double pv = aug[c][c];
        __syncthreads();
        for (int k = tid; k < 104; k += 64) aug[c][k] /= pv;
        __syncthreads();
        if (tid < 52 && tid != c) {
            double f = aug[tid][c];
            for (int k = 0; k < 104; ++k) aug[tid][k] -= f * aug[c][k];
        }
        __syncthreads();
    }

    // MiT[k][j] = Qinv[j][k]
    for (int idx = tid; idx < 2500; idx += 64) {
        int k = idx / 50, j = idx % 50;
        Mout[idx] = (float)aug[j][52 + k];
    }
}

// ---------------------------------------------------------------------------
// Transpose Z[BATCH][C] -> ZT[C][BATCH], 64 rows per block.
// ---------------------------------------------------------------------------
template <int C>
__global__ __launch_bounds__(64)
void transp(const float* __restrict__ Z, float* __restrict__ ZT)
{
    __shared__ float t[64][C + 1];
    const int lane = threadIdx.x;
    const size_t r0 = (size_t)blockIdx.x * 64;
#pragma unroll 1
    for (int i = 0; i < C; ++i) {
        int idx = i * 64 + lane;
        int r = idx / C, c = idx % C;
        t[r][c] = Z[r0 * C + idx];
    }
    __syncthreads();
#pragma unroll 1
    for (int c = 0; c < C; ++c)
        ZT[(size_t)c * BATCH + r0 + lane] = t[lane][c];
}

// ---------------------------------------------------------------------------
// Transpose + triple-split W[K][N] f32 -> Wt{h,m,l}[N][K] bf16.
// ---------------------------------------------------------------------------
__global__ __launch_bounds__(256)
void wsplit(const float* __restrict__ W, ushort_t* __restrict__ WH,
            ushort_t* __restrict__ WM, ushort_t* __restrict__ WL, int K, int N)
{
    __shared__ float tile[32][33];
    int t = threadIdx.x;
    int n0 = blockIdx.x * 32, k0 = blockIdx.y * 32;
    int rr = t >> 5, cc = t & 31;
#pragma unroll
    for (int i = 0; i < 4; ++i)
        tile[rr + i * 8][cc] = W[(size_t)(k0 + rr + i * 8) * N + n0 + cc];
    __syncthreads();
#pragma unroll
    for (int i = 0; i < 4; ++i) {
        int n = n0 + rr + i * 8, k = k0 + cc;
        float f = tile[cc][rr + i * 8];
        ushort_t h, m, l;
        split3(f, h, m, l);
        WH[(size_t)n * K + k] = h;
        WM[(size_t)n * K + k] = m;
        WL[(size_t)n * K + k] = l;
    }
}

// ---------------------------------------------------------------------------
// MFMA GEMM, fp32-emulated via bf16 triple split (6 MFMAs per frag pair).
// ---------------------------------------------------------------------------
template <int BN_APPLY>
__global__ __launch_bounds__(256)
void gemm_mfma(const float* __restrict__ A,
               const ushort_t* __restrict__ WH, const ushort_t* __restrict__ WM,
               const ushort_t* __restrict__ WL,
               const float* __restrict__ bias,
               const float* __restrict__ scale, const float* __restrict__ shift,
               float* __restrict__ C, int M, int K, int N)
{
    const int TIER = 128 * 80;
    __shared__ __attribute__((aligned(16))) unsigned char lds[6 * 128 * 80];
    char* Lb = (char*)lds;

    const int t = threadIdx.x;
    const int r = t >> 1, kh = t & 1;
    const int row0 = blockIdx.x * 128, col0 = blockIdx.y * 128;

    const float*    Ab  = A  + (size_t)(row0 + r) * K + kh * 16;
    const ushort_t* WHb = WH + (size_t)(col0 + r) * K + kh * 16;
    const ushort_t* WMb = WM + (size_t)(col0 + r) * K + kh * 16;
    const ushort_t* WLb = WL + (size_t)(col0 + r) * K + kh * 16;
    const int awb = r * 80 + kh * 32;

    const int lane = t & 63, w = t >> 6;
    const int wm = w >> 1, wn = w & 1;
    const int fr = lane & 15, fg = lane >> 4;
    const int aoff = (wm * 64 + fr) * 80 + fg * 16;
    const int boff = 3 * TIER + (wn * 64 + fr) * 80 + fg * 16;

    f32x4 acc[4][4];
#pragma unroll
    for (int m = 0; m < 4; ++m)
#pragma unroll
        for (int n = 0; n < 4; ++n)
#pragma unroll
            for (int q = 0; q < 4; ++q) acc[m][n][q] = 0.f;

    for (int k0 = 0; k0 < K; k0 += 32) {
        float4 f[4];
#pragma unroll
        for (int i = 0; i < 4; ++i) f[i] = *(const float4*)(Ab + k0 + i * 4);
        if (BN_APPLY) {
#pragma unroll
            for (int i = 0; i < 4; ++i) {
                float4 sc = *(const float4*)(scale + k0 + kh * 16 + i * 4);
                float4 sh = *(const float4*)(shift + k0 + kh * 16 + i * 4);
                f[i].x = fmaxf(f[i].x * sc.x + sh.x, 0.f);
                f[i].y = fmaxf(f[i].y * sc.y + sh.y, 0.f);
                f[i].z = fmaxf(f[i].z * sc.z + sh.z, 0.f);
                f[i].w = fmaxf(f[i].w * sc.w + sh.w, 0.f);
            }
        }
        ushort_t hh[16], mm[16], ll[16];
#pragma unroll
        for (int i = 0; i < 4; ++i) {
            split3(f[i].x, hh[i*4+0], mm[i*4+0], ll[i*4+0]);
            split3(f[i].y, hh[i*4+1], mm[i*4+1], ll[i*4+1]);
            split3(f[i].z, hh[i*4+2], mm[i*4+2], ll[i*4+2]);
            split3(f[i].w, hh[i*4+3], mm[i*4+3], ll[i*4+3]);
        }
#define PK(a,b) (((unsigned)(a)) | (((unsigned)(b)) << 16))
        *(uint4*)(Lb + awb)              = make_uint4(PK(hh[0],hh[1]), PK(hh[2],hh[3]), PK(hh[4],hh[5]), PK(hh[6],hh[7]));
        *(uint4*)(Lb + awb + 16)         = make_uint4(PK(hh[8],hh[9]), PK(hh[10],hh[11]), PK(hh[12],hh[13]), PK(hh[14],hh[15]));
        *(uint4*)(Lb + TIER + awb)       = make_uint4(PK(mm[0],mm[1]), PK(mm[2],mm[3]), PK(mm[4],mm[5]), PK(mm[6],mm[7]));
        *(uint4*)(Lb + TIER + awb + 16)  = make_uint4(PK(mm[8],mm[9]), PK(mm[10],mm[11]), PK(mm[12],mm[13]), PK(mm[14],mm[15]));
        *(uint4*)(Lb + 2*TIER + awb)     = make_uint4(PK(ll[0],ll[1]), PK(ll[2],ll[3]), PK(ll[4],ll[5]), PK(ll[6],ll[7]));
        *(uint4*)(Lb + 2*TIER + awb + 16)= make_uint4(PK(ll[8],ll[9]), PK(ll[10],ll[11]), PK(ll[12],ll[13]), PK(ll[14],ll[15]));
#undef PK
        {
            const uint4* p0 = (const uint4*)(WHb + k0);
            const uint4* p1 = (const uint4*)(WMb + k0);
            const uint4* p2 = (const uint4*)(WLb + k0);
            *(uint4*)(Lb + 3*TIER + awb)      = p0[0];
            *(uint4*)(Lb + 3*TIER + awb + 16) = p0[1];
            *(uint4*)(Lb + 4*TIER + awb)      = p1[0];
            *(uint4*)(Lb + 4*TIER + awb + 16) = p1[1];
            *(uint4*)(Lb + 5*TIER + awb)      = p2[0];
            *(uint4*)(Lb + 5*TIER + awb + 16) = p2[1];
        }
        __syncthreads();

        short8 ah[4], am4[4], al4[4], bh[4], bm4[4], bl4[4];
#pragma unroll
        for (int m = 0; m < 4; ++m) {
            ah[m]  = *(short8*)(Lb + aoff + m * 1280);
            am4[m] = *(short8*)(Lb + TIER + aoff + m * 1280);
            al4[m] = *(short8*)(Lb + 2 * TIER + aoff + m * 1280);
        }
#pragma unroll
        for (int n = 0; n < 4; ++n) {
            bh[n]  = *(short8*)(Lb + boff + n * 1280);
            bm4[n] = *(short8*)(Lb + TIER + boff + n * 1280);
            bl4[n] = *(short8*)(Lb + 2 * TIER + boff + n * 1280);
        }
#pragma unroll
        for (int m = 0; m < 4; ++m)
#pragma unroll
            for (int n = 0; n < 4; ++n) {
                f32x4 c = acc[m][n];
                c = __builtin_amdgcn_mfma_f32_16x16x32_bf16(al4[m], bh[n],  c, 0, 0, 0);
                c = __builtin_amdgcn_mfma_f32_16x16x32_bf16(ah[m],  bl4[n], c, 0, 0, 0);
                c = __builtin_amdgcn_mfma_f32_16x16x32_bf16(am4[m], bm4[n], c, 0, 0, 0);
                c = __builtin_amdgcn_mfma_f32_16x16x32_bf16(am4[m], bh[n],  c, 0, 0, 0);
                c = __builtin_amdgcn_mfma_f32_16x16x32_bf16(ah[m],  bm4[n], c, 0, 0, 0);
                c = __builtin_amdgcn_mfma_f32_16x16x32_bf16(ah[m],  bh[n],  c, 0, 0, 0);
                acc[m][n] = c;
            }
        __syncthreads();
    }

#pragma unroll
    for (int m = 0; m < 4; ++m)
#pragma unroll
        for (int n = 0; n < 4; ++n) {
            int cc = col0 + wn * 64 + n * 16 + fr;
            float b = bias[cc];
#pragma unroll
            for (int q = 0; q < 4; ++q) {
                int rr = row0 + wm * 64 + m * 16 + fg * 4 + q;
                C[(size_t)rr * N + cc] = acc[m][n][q] + b;
            }
        }
}

// ---------------------------------------------------------------------------
// fp32 tiled GEMM (GEMM1 K=50, GEMM4 N=100).
// ---------------------------------------------------------------------------
template <int BN_APPLY>
__global__ __launch_bounds__(256)
void gemm_k(const float* __restrict__ A, const float* __restrict__ W,
            const float* __restrict__ bias,
            const float* __restrict__ scale, const float* __restrict__ shift,
            float* __restrict__ C, int M, int K, int N)
{
    const int BM = 128, BN = 128, BK = 16;
    __shared__ __attribute__((aligned(16))) float As[BK][BM + 4];
    __shared__ __attribute__((aligned(16))) float Ws[BK][BN];
    int tid = threadIdx.x;
    int tm = tid >> 4, tn = tid & 15;
    int row0 = blockIdx.x * BM, col0 = blockIdx.y * BN;

    float acc[8][8];
#pragma unroll
    for (int i = 0; i < 8; ++i)
#pragma unroll
        for (int j = 0; j < 8; ++j) acc[i][j] = 0.f;

    int alr = tid >> 4;
    int alk = tid & 15;
    int wlc = tid & 127;
    int wlk = tid >> 7;

    for (int k0 = 0; k0 < K; k0 += BK) {
#pragma unroll
        for (int i = 0; i < 8; ++i) {
            int rr = row0 + alr + i * 16;
            int kk = k0 + alk;
            float v = 0.f;
            if (kk < K) {
                v = A[(size_t)rr * K + kk];
                if (BN_APPLY) v = fmaxf(v * scale[kk] + shift[kk], 0.f);
            }
            As[alk][alr + i * 16] = v;
        }
#pragma unroll
        for (int i = 0; i < 8; ++i) {
            int kk = k0 + wlk + i * 2;
            int cc = col0 + wlc;
            Ws[wlk + i * 2][wlc] = (kk < K && cc < N) ? W[(size_t)kk * N + cc] : 0.f;
        }
        __syncthreads();
#pragma unroll
        for (int kk = 0; kk < BK; ++kk) {
            float av[8], wv[8];
            float4 tv;
            tv = *(const float4*)&As[kk][tm * 8];     av[0]=tv.x; av[1]=tv.y; av[2]=tv.z; av[3]=tv.w;
            tv = *(const float4*)&As[kk][tm * 8 + 4]; av[4]=tv.x; av[5]=tv.y; av[6]=tv.z; av[7]=tv.w;
            tv = *(const float4*)&Ws[kk][tn * 8];     wv[0]=tv.x; wv[1]=tv.y; wv[2]=tv.z; wv[3]=tv.w;
            tv = *(const float4*)&Ws[kk][tn * 8 + 4]; wv[4]=tv.x; wv[5]=tv.y; wv[6]=tv.z; wv[7]=tv.w;
#pragma unroll
            for (int i = 0; i < 8; ++i)
#pragma unroll
                for (int j = 0; j < 8; ++j) acc[i][j] += av[i] * wv[j];
        }
        __syncthreads();
    }
#pragma unroll
    for (int i = 0; i < 8; ++i) {
        int rr = row0 + tm * 8 + i;
#pragma unroll
        for (int j = 0; j < 8; ++j) {
            int cc = col0 + tn * 8 + j;
            if (cc < N) C[(size_t)rr * N + cc] = acc[i][j] + bias[cc];
        }
    }
}

// ---------------------------------------------------------------------------
// BatchNorm stats.
// ---------------------------------------------------------------------------
__global__ __launch_bounds__(256)
void stats_part(const float* __restrict__ Z, float* __restrict__ ps,
                float* __restrict__ pq, int M, int C, int chunks)
{
    int lc = threadIdx.x & 63;
    int col = blockIdx.x * 64 + lc;
    int rg = threadIdx.x >> 6;
    int rpc = M / chunks;
    int r0 = blockIdx.y * rpc;
    float s = 0.f, q = 0.f;
    for (int rr = r0 + rg; rr < r0 + rpc; rr += 4) {
        float v = Z[(size_t)rr * C + col];
        s += v; q += v * v;
    }
    __shared__ float ls[4][64], lq[4][64];
    ls[rg][lc] = s; lq[rg][lc] = q;
    __syncthreads();
    if (rg == 0) {
        float S = ls[0][lc] + ls[1][lc] + ls[2][lc] + ls[3][lc];
        float Q = lq[0][lc] + lq[1][lc] + lq[2][lc] + lq[3][lc];
        ps[(size_t)blockIdx.y * C + col] = S;
        pq[(size_t)blockIdx.y * C + col] = Q;
    }
}

__global__ void stats_fin(const float* __restrict__ ps, const float* __restrict__ pq,
                          const float* __restrict__ g, const float* __restrict__ be,
                          float* __restrict__ scale, float* __restrict__ shift,
                          int C, int M, int chunks)
{
    int c = blockIdx.x * blockDim.x + threadIdx.x;
    if (c >= C) return;
    float S = 0.f, Q = 0.f;
    for (int i = 0; i < chunks; ++i) { S += ps[(size_t)i * C + c]; Q += pq[(size_t)i * C + c]; }
    float inv = 1.0f / (float)M;
    float mean = S * inv;
    float var = Q * inv - mean * mean;
    float rstd = 1.0f / sqrtf(var + EPSBN);
    float sc = g[c] * rstd;
    scale[c] = sc;
    shift[c] = be[c] - mean * sc;
}

// ---------------------------------------------------------------------------
// Fused 15-iteration ADMM. xi/rh/xin in REGISTERS (fully unrolled, ~170 live
// VGPRs -> no spill); lam in LDS [k][lane] (off the critical path). Barrier-
// free: each lane touches only its own LDS column. Matvec fully unrolled:
// contiguous s_loads of MiT rows + 50 independent v_fmac per k (no chains).
// ---------------------------------------------------------------------------
__global__ __launch_bounds__(64, 1)
void iter_k(const float* __restrict__ XT, const float* __restrict__ NNT,
            const float* __restrict__ MiT, float* __restrict__ out)
{
    __shared__ float sLam[50 * 64];
    const int lane = threadIdx.x;
    const int row = blockIdx.x * 64 + lane;

    float xi[50], rh[50], xin[50];
#pragma unroll
    for (int k = 0; k < 50; ++k) xi[k] = NNT[(size_t)k * BATCH + row];
#pragma unroll
    for (int k = 0; k < 50; ++k) sLam[(k << 6) + lane] = NNT[(size_t)(50 + k) * BATCH + row];

    float fps = 0.f, prs = 0.f;

#pragma unroll 1
    for (int it = 0; it < 15; ++it) {
        // ---- pass 1: rh = A^T min(b, A xi) (registers, unrolled)
#pragma unroll
        for (int k = 0; k < 50; ++k) rh[k] = 0.f;
        {
            float pre = 0.f, Sp = 0.f, ap = 0.f;
#pragma unroll
            for (int k = 0; k < 50; ++k) {
                rh[k] += fminf(VMAX, xi[k]) - fminf(VMAX, -xi[k]);
                rh[k] -= TF * Sp;
                pre += xi[k];
                float p = TF * pre;
                Sp += fminf(PMAX, p) - fminf(PMAX, -p);
                if (k < 49) {
                    float a = AF * (xi[k + 1] - xi[k]);
                    float da = fminf(AMAX, a) - fminf(AMAX, -a);
                    rh[k] -= AF * da; rh[k + 1] += AF * da;
                    if (k >= 1) {
                        float j = AF * (a - ap);
                        float dj = fminf(JMAX, j) - fminf(JMAX, -j);
                        rh[k - 1] += JF * dj; rh[k] -= 2.f * JF * dj; rh[k + 1] += JF * dj;
                    }
                    ap = a;
                }
            }
            float Stot = TF * Sp;
            // combine: rh += lam (LDS) + x (L3-resident) + Stot
#pragma unroll
            for (int k = 0; k < 50; ++k)
                rh[k] = rh[k] + sLam[(k << 6) + lane] + XT[(size_t)k * BATCH + row] + Stot;
        }

        // ---- xin[j] = sum_k MiT[k][j] * rh[k]; all compile-time indices
#pragma unroll
        for (int j = 0; j < 50; ++j) xin[j] = 0.f;
#pragma unroll
        for (int k = 0; k < 50; ++k) {
            float rv = rh[k];
#pragma unroll
            for (int j = 0; j < 50; ++j)
                xin[j] += MiT[k * 50 + j] * rv;
        }

        // ---- pass 2: residual/s norms + g (into rh regs), unrolled
        float res2 = 0.f, ds2 = 0.f, dxi2 = 0.f, dlam2 = 0.f;
#pragma unroll
        for (int k = 0; k < 50; ++k) rh[k] = 0.f;
        {
            float preo = 0.f, pren = 0.f, SpF = 0.f, aop = 0.f, anp = 0.f;
#pragma unroll
            for (int k = 0; k < 50; ++k) {
                float xoc = xi[k], xnc = xin[k];
                float d = xoc - xnc; dxi2 += d * d;
                float rp = fmaxf(xnc - VMAX, 0.f), rm = fmaxf(-xnc - VMAX, 0.f);
                res2 += rp * rp + rm * rm;
                float so = fmaxf(VMAX - xoc, 0.f), sn = fmaxf(VMAX - xnc, 0.f);
                d = so - sn; ds2 += d * d;
                so = fmaxf(VMAX + xoc, 0.f); sn = fmaxf(VMAX + xnc, 0.f);
                d = so - sn; ds2 += d * d;
                rh[k] += rp - rm;
                rh[k] -= TF * SpF;
                preo += xoc; pren += xnc;
                float po = TF * preo, pn = TF * pren;
                rp = fmaxf(pn - PMAX, 0.f); rm = fmaxf(-pn - PMAX, 0.f);
                res2 += rp * rp + rm * rm;
                so = fmaxf(PMAX - po, 0.f); sn = fmaxf(PMAX - pn, 0.f);
                d = so - sn; ds2 += d * d;
                so = fmaxf(PMAX + po, 0.f); sn = fmaxf(PMAX + pn, 0.f);
                d = so - sn; ds2 += d * d;
                SpF += rp - rm;
                if (k < 49) {
                    float ao = AF * (xi[k + 1] - xoc), an = AF * (xin[k + 1] - xnc);
                    rp = fmaxf(an - AMAX, 0.f); rm = fmaxf(-an - AMAX, 0.f);
                    res2 += rp * rp + rm * rm;
                    so = fmaxf(AMAX - ao, 0.f); sn = fmaxf(AMAX - an, 0.f);
                    d = so - sn; ds2 += d * d;
                    so = fmaxf(AMAX + ao, 0.f); sn = fmaxf(AMAX + an, 0.f);
                    d = so - sn; ds2 += d * d;
                    float fa = rp - rm; rh[k] -= AF * fa; rh[k + 1] += AF * fa;
                    if (k >= 1) {
                        float jo = AF * (ao - aop), jn = AF * (an - anp);
                        rp = fmaxf(jn - JMAX, 0.f); rm = fmaxf(-jn - JMAX, 0.f);
                        res2 += rp * rp + rm * rm;
                        so = fmaxf(JMAX - jo, 0.f); sn = fmaxf(JMAX - jn, 0.f);
                        d = so - sn; ds2 += d * d;
                        so = fmaxf(JMAX + jo, 0.f); sn = fmaxf(JMAX + jn, 0.f);
                        d = so - sn; ds2 += d * d;
                        float fj = rp - rm;
                        rh[k - 1] += JF * fj; rh[k] -= 2.f * JF * fj; rh[k + 1] += JF * fj;
                    }
                    aop = ao; anp = an;
                }
            }
            float SF = TF * SpF;
#pragma unroll
            for (int k = 0; k < 50; ++k) {
                float gk = rh[k] + SF;
                dlam2 += gk * gk;
                sLam[(k << 6) + lane] -= gk;
            }
        }
        prs += sqrtf(res2);
        fps += sqrtf(dxi2) + sqrtf(dlam2) + sqrtf(ds2);
#pragma unroll
        for (int k = 0; k < 50; ++k) xi[k] = xin[k];
    }
#pragma unroll
    for (int k = 0; k < 50; ++k) out[(size_t)row * 50 + k] = xi[k];
    out[(size_t)BATCH * 50 + row] = fps * (1.f / 15.f);
    out[(size_t)BATCH * 51 + row] = prs * (1.f / 15.f);
}

// ---------------------------------------------------------------------------
extern "C" void kernel_launch(void* const* d_in, const int* in_sizes, int n_in,
                              void* d_out, int out_size, void* d_ws, size_t ws_size,
                              hipStream_t stream)
{
    const float* x   = (const float*)d_in[0];
    const float* W1  = (const float*)d_in[1];
    const float* b1  = (const float*)d_in[2];
    const float* g1  = (const float*)d_in[3];
    const float* be1 = (const float*)d_in[4];
    const float* W2  = (const float*)d_in[5];
    const float* b2  = (const float*)d_in[6];
    const float* g2  = (const float*)d_in[7];
    const float* be2 = (const float*)d_in[8];
    const float* W3  = (const float*)d_in[9];
    const float* b3  = (const float*)d_in[10];
    const float* g3  = (const float*)d_in[11];
    const float* be3 = (const float*)d_in[12];
    const float* W4  = (const float*)d_in[13];
    const float* b4  = (const float*)d_in[14];

    float *z1, *z2, *ps, *pq, *scb, *shb, *Mi, *xT, *nnT;
    ushort_t *w2h, *w2m, *w2l, *w3h, *w3m, *w3l;
    hipGetSymbolAddress((void**)&z1,  HIP_SYMBOL(g_z1));
    hipGetSymbolAddress((void**)&z2,  HIP_SYMBOL(g_z2));
    hipGetSymbolAddress((void**)&ps,  HIP_SYMBOL(g_ps));
    hipGetSymbolAddress((void**)&pq,  HIP_SYMBOL(g_pq));
    hipGetSymbolAddress((void**)&scb, HIP_SYMBOL(g_scale));
    hipGetSymbolAddress((void**)&shb, HIP_SYMBOL(g_shift));
    hipGetSymbolAddress((void**)&Mi,  HIP_SYMBOL(g_Mi));
    hipGetSymbolAddress((void**)&xT,  HIP_SYMBOL(g_xT));
    hipGetSymbolAddress((void**)&nnT, HIP_SYMBOL(g_nnT));
    hipGetSymbolAddress((void**)&w2h, HIP_SYMBOL(g_w2h));
    hipGetSymbolAddress((void**)&w2m, HIP_SYMBOL(g_w2m));
    hipGetSymbolAddress((void**)&w2l, HIP_SYMBOL(g_w2l));
    hipGetSymbolAddress((void**)&w3h, HIP_SYMBOL(g_w3h));
    hipGetSymbolAddress((void**)&w3m, HIP_SYMBOL(g_w3m));
    hipGetSymbolAddress((void**)&w3l, HIP_SYMBOL(g_w3l));

    float* z3  = z1;                        // z1 dead after GEMM2
    float* nno = z1 + (size_t)BATCH * H3;   // after z3
    float* sc1 = scb;        float* sh1 = shb;
    float* sc2 = scb + 1024; float* sh2 = shb + 1024;
    float* sc3 = scb + 2048; float* sh3 = shb + 2048;

    dim3 blk(256);
    hipLaunchKernelGGL(build_M, dim3(1), dim3(64), 0, stream, Mi);
    hipLaunchKernelGGL(wsplit, dim3(H2 / 32, H1 / 32), blk, 0, stream, W2, w2h, w2m, w2l, H1, H2);
    hipLaunchKernelGGL(wsplit, dim3(H3 / 32, H2 / 32), blk, 0, stream, W3, w3h, w3m, w3l, H2, H3);
    hipLaunchKernelGGL((transp<50>), dim3(BATCH / 64), dim3(64), 0, stream, x, xT);

    // L1: z1 = x @ W1 + b1 (fp32 vector path, K=50)
    hipLaunchKernelGGL((gemm_k<0>), dim3(BATCH / 128, H1 / 128), blk, 0, stream,
                       x, W1, b1, (const float*)nullptr, (const float*)nullptr,
                       z1, BATCH, NVARS, H1);
    hipLaunchKernelGGL(stats_part, dim3(H1 / 64, 32), blk, 0, stream, z1, ps, pq, BATCH, H1, 32);
    hipLaunchKernelGGL(stats_fin, dim3(4), dim3(256), 0, stream, ps, pq, g1, be1, sc1, sh1, H1, BATCH, 32);
    // L2: z2 = relu(bn(z1)) @ W2 + b2 (MFMA split)
    hipLaunchKernelGGL((gemm_mfma<1>), dim3(BATCH / 128, H2 / 128), blk, 0, stream,
                       z1, w2h, w2m, w2l, b2, sc1, sh1, z2, BATCH, H1, H2);
    hipLaunchKernelGGL(stats_part, dim3(H2 / 64, 32), blk, 0, stream, z2, ps, pq, BATCH, H2, 32);
    hipLaunchKernelGGL(stats_fin, dim3(4), dim3(256), 0, stream, ps, pq, g2, be2, sc2, sh2, H2, BATCH, 32);
    // L3: z3 = relu(bn(z2)) @ W3 + b3 (MFMA split)
    hipLaunchKernelGGL((gemm_mfma<1>), dim3(BATCH / 128, H3 / 128), blk, 0, stream,
                       z2, w3h, w3m, w3l, b3, sc2, sh2, z3, BATCH, H2, H3);
    hipLaunchKernelGGL(stats_part, dim3(H3 / 64, 32), blk, 0, stream, z3, ps, pq, BATCH, H3, 32);
    hipLaunchKernelGGL(stats_fin, dim3(1), dim3(256), 0, stream, ps, pq, g3, be3, sc3, sh3, H3, BATCH, 32);
    // L4: nno = relu(bn(z3)) @ W4 + b4 (fp32 vector path, N=100)
    hipLaunchKernelGGL((gemm_k<1>), dim3(BATCH / 128, 1), blk, 0, stream,
                       z3, W4, b4, sc3, sh3, nno, BATCH, H3, NOUT);
    hipLaunchKernelGGL((transp<100>), dim3(BATCH / 64), dim3(64), 0, stream, nno, nnT);
    // fused ADMM iterations (register-resident, barrier-free)
    hipLaunchKernelGGL(iter_k, dim3(BATCH / 64), dim3(64), 0, stream,
                       xT, nnT, Mi, (float*)d_out);
}

// Round 6
// 1933.613 us; speedup vs baseline: 1.3593x; 1.2935x over previous
//
#include <hip/hip_runtime.h>
#include <math.h>

#define BATCH 32768
#define NVARS 50
#define H1 1024
#define H2 1024
#define H3 256
#define NOUT 100
#define EPSBN 1e-5f

#define TF   0.05f
#define AF   20.0f
#define JF   400.0f
#define VMAX 1.0f
#define AMAX 2.0f
#define JMAX 5.0f
#define PMAX 3.14159265358979323846f

typedef unsigned short ushort_t;
typedef __attribute__((ext_vector_type(8))) short short8;
typedef __attribute__((ext_vector_type(4))) float f32x4;

// ---------------------------------------------------------------------------
// Device-global scratch (no ws_size dependence).
// ---------------------------------------------------------------------------
__device__ float g_z1[(size_t)BATCH * H1];   // z1 / (z3, nno reuse)
__device__ float g_z2[(size_t)BATCH * H2];
__device__ float g_ps[32 * 1024];
__device__ float g_pq[32 * 1024];
__device__ float g_scale[3 * 1024];
__device__ float g_shift[3 * 1024];
__device__ float g_Mi[2500];
__device__ float g_xT[(size_t)NVARS * BATCH];   // x transposed [50][BATCH]
__device__ float g_nnT[(size_t)NOUT * BATCH];   // nn out transposed [100][BATCH]
__device__ ushort_t g_w2h[(size_t)H1 * H2], g_w2m[(size_t)H1 * H2], g_w2l[(size_t)H1 * H2];
__device__ ushort_t g_w3h[(size_t)H2 * H3], g_w3m[(size_t)H2 * H3], g_w3l[(size_t)H2 * H3];

// ---------------------------------------------------------------------------
// float -> bf16 triple split (RNE), f ~= hi + mid + lo with rel err ~2^-26.
// ---------------------------------------------------------------------------
__device__ __forceinline__ void split3(float f, ushort_t& h, ushort_t& m, ushort_t& l)
{
    unsigned u = __float_as_uint(f);
    unsigned r = u + 0x7fffu + ((u >> 16) & 1u);
    h = (ushort_t)(r >> 16);
    float f1 = f - __uint_as_float((unsigned)h << 16);
    unsigned u1 = __float_as_uint(f1);
    unsigned r1 = u1 + 0x7fffu + ((u1 >> 16) & 1u);
    m = (ushort_t)(r1 >> 16);
    float f2 = f1 - __uint_as_float((unsigned)m << 16);
    unsigned u2 = __float_as_uint(f2);
    unsigned r2 = u2 + 0x7fffu + ((u2 >> 16) & 1u);
    l = (ushort_t)(r2 >> 16);
}

// ---------------------------------------------------------------------------
// Build MiT[k*50+j] = Q_inv[j][k] (transposed) via f64 Gauss-Jordan w/ pivot.
// ---------------------------------------------------------------------------
__global__ void build_M(float* __restrict__ Mout)
{
    __shared__ double aug[52][104];
    __shared__ int piv;
    int tid = threadIdx.x;

    const double Tf = (double)0.05f;
    const double c3[3] = { 400.0, -800.0, 400.0 };

    for (int idx = tid; idx < 52 * 104; idx += 64) {
        int j = idx / 104, k = idx % 104;
        double v = 0.0;
        if (k >= 52) {
            v = (k == 52 + j) ? 1.0 : 0.0;
        } else if (j < 50 && k < 50) {
            double q = (j == k) ? 3.0 : 0.0;
            if (j == k) q += 800.0 * ((j < 49 ? 1 : 0) + (j > 0 ? 1 : 0));
            if (j - k == 1 || k - j == 1) q += -800.0;
            int lo = j > k ? j : k; lo -= 2; if (lo < 0) lo = 0;
            int hi = j < k ? j : k; if (hi > 47) hi = 47;
            for (int i = lo; i <= hi; ++i) {
                int dj = j - i, dk = k - i;
                if (dj >= 0 && dj <= 2 && dk >= 0 && dk <= 2)
                    q += 2.0 * c3[dj] * c3[dk];
            }
            int mx = j > k ? j : k;
            q += 2.0 * Tf * Tf * (double)(50 - mx);
            v = q;
        } else if ((j == 50 && k == 0) || (j == 0 && k == 50) ||
                   (j == 51 && k == 49) || (j == 49 && k == 51)) {
            v = 1.0;
        }
        aug[j][k] = v;
    }
    __syncthreads();

    for (int c = 0; c < 52; ++c) {
        if (tid == 0) {
            int p = c; double best = fabs(aug[c][c]);
            for (int r = c + 1; r < 52; ++r) {
                double v = fabs(aug[r][c]);
                if (v > best) { best = v; p = r; }
            }
            piv = p;
        }
        __syncthreads();
        int p = piv;
        if (p != c) {
            for (int k = tid; k < 104; k += 64) {
                double t = aug[c][k]; aug[c][k] = aug[p][k]; aug[p][k] = t;
            }
        }
        __syncthreads();
        double pv = aug[c][c];
        __syncthreads();
        for (int k = tid; k < 104; k += 64) aug[c][k] /= pv;
        __syncthreads();
        if (tid < 52 && tid != c) {
            double f = aug[tid][c];
            for (int k = 0; k < 104; ++k) aug[tid][k] -= f * aug[c][k];
        }
        __syncthreads();
    }

    // MiT[k][j] = Qinv[j][k]
    for (int idx = tid; idx < 2500; idx += 64) {
        int k = idx / 50, j = idx % 50;
        Mout[idx] = (float)aug[j][52 + k];
    }
}

// ---------------------------------------------------------------------------
// Transpose Z[BATCH][C] -> ZT[C][BATCH], 64 rows per block.
// ---------------------------------------------------------------------------
template <int C>
__global__ __launch_bounds__(64)
void transp(const float* __restrict__ Z, float* __restrict__ ZT)
{
    __shared__ float t[64][C + 1];
    const int lane = threadIdx.x;
    const size_t r0 = (size_t)blockIdx.x * 64;
#pragma unroll 1
    for (int i = 0; i < C; ++i) {
        int idx = i * 64 + lane;
        int r = idx / C, c = idx % C;
        t[r][c] = Z[r0 * C + idx];
    }
    __syncthreads();
#pragma unroll 1
    for (int c = 0; c < C; ++c)
        ZT[(size_t)c * BATCH + r0 + lane] = t[lane][c];
}

// ---------------------------------------------------------------------------
// Transpose + triple-split W[K][N] f32 -> Wt{h,m,l}[N][K] bf16.
// ---------------------------------------------------------------------------
__global__ __launch_bounds__(256)
void wsplit(const float* __restrict__ W, ushort_t* __restrict__ WH,
            ushort_t* __restrict__ WM, ushort_t* __restrict__ WL, int K, int N)
{
    __shared__ float tile[32][33];
    int t = threadIdx.x;
    int n0 = blockIdx.x * 32, k0 = blockIdx.y * 32;
    int rr = t >> 5, cc = t & 31;
#pragma unroll
    for (int i = 0; i < 4; ++i)
        tile[rr + i * 8][cc] = W[(size_t)(k0 + rr + i * 8) * N + n0 + cc];
    __syncthreads();
#pragma unroll
    for (int i = 0; i < 4; ++i) {
        int n = n0 + rr + i * 8, k = k0 + cc;
        float f = tile[cc][rr + i * 8];
        ushort_t h, m, l;
        split3(f, h, m, l);
        WH[(size_t)n * K + k] = h;
        WM[(size_t)n * K + k] = m;
        WL[(size_t)n * K + k] = l;
    }
}

// ---------------------------------------------------------------------------
// MFMA GEMM, fp32-emulated via bf16 triple split (6 MFMAs per frag pair).
// ---------------------------------------------------------------------------
template <int BN_APPLY>
__global__ __launch_bounds__(256)
void gemm_mfma(const float* __restrict__ A,
               const ushort_t* __restrict__ WH, const ushort_t* __restrict__ WM,
               const ushort_t* __restrict__ WL,
               const float* __restrict__ bias,
               const float* __restrict__ scale, const float* __restrict__ shift,
               float* __restrict__ C, int M, int K, int N)
{
    const int TIER = 128 * 80;
    __shared__ __attribute__((aligned(16))) unsigned char lds[6 * 128 * 80];
    char* Lb = (char*)lds;

    const int t = threadIdx.x;
    const int r = t >> 1, kh = t & 1;
    const int row0 = blockIdx.x * 128, col0 = blockIdx.y * 128;

    const float*    Ab  = A  + (size_t)(row0 + r) * K + kh * 16;
    const ushort_t* WHb = WH + (size_t)(col0 + r) * K + kh * 16;
    const ushort_t* WMb = WM + (size_t)(col0 + r) * K + kh * 16;
    const ushort_t* WLb = WL + (size_t)(col0 + r) * K + kh * 16;
    const int awb = r * 80 + kh * 32;

    const int lane = t & 63, w = t >> 6;
    const int wm = w >> 1, wn = w & 1;
    const int fr = lane & 15, fg = lane >> 4;
    const int aoff = (wm * 64 + fr) * 80 + fg * 16;
    const int boff = 3 * TIER + (wn * 64 + fr) * 80 + fg * 16;

    f32x4 acc[4][4];
#pragma unroll
    for (int m = 0; m < 4; ++m)
#pragma unroll
        for (int n = 0; n < 4; ++n)
#pragma unroll
            for (int q = 0; q < 4; ++q) acc[m][n][q] = 0.f;

    for (int k0 = 0; k0 < K; k0 += 32) {
        float4 f[4];
#pragma unroll
        for (int i = 0; i < 4; ++i) f[i] = *(const float4*)(Ab + k0 + i * 4);
        if (BN_APPLY) {
#pragma unroll
            for (int i = 0; i < 4; ++i) {
                float4 sc = *(const float4*)(scale + k0 + kh * 16 + i * 4);
                float4 sh = *(const float4*)(shift + k0 + kh * 16 + i * 4);
                f[i].x = fmaxf(f[i].x * sc.x + sh.x, 0.f);
                f[i].y = fmaxf(f[i].y * sc.y + sh.y, 0.f);
                f[i].z = fmaxf(f[i].z * sc.z + sh.z, 0.f);
                f[i].w = fmaxf(f[i].w * sc.w + sh.w, 0.f);
            }
        }
        ushort_t hh[16], mm[16], ll[16];
#pragma unroll
        for (int i = 0; i < 4; ++i) {
            split3(f[i].x, hh[i*4+0], mm[i*4+0], ll[i*4+0]);
            split3(f[i].y, hh[i*4+1], mm[i*4+1], ll[i*4+1]);
            split3(f[i].z, hh[i*4+2], mm[i*4+2], ll[i*4+2]);
            split3(f[i].w, hh[i*4+3], mm[i*4+3], ll[i*4+3]);
        }
#define PK(a,b) (((unsigned)(a)) | (((unsigned)(b)) << 16))
        *(uint4*)(Lb + awb)              = make_uint4(PK(hh[0],hh[1]), PK(hh[2],hh[3]), PK(hh[4],hh[5]), PK(hh[6],hh[7]));
        *(uint4*)(Lb + awb + 16)         = make_uint4(PK(hh[8],hh[9]), PK(hh[10],hh[11]), PK(hh[12],hh[13]), PK(hh[14],hh[15]));
        *(uint4*)(Lb + TIER + awb)       = make_uint4(PK(mm[0],mm[1]), PK(mm[2],mm[3]), PK(mm[4],mm[5]), PK(mm[6],mm[7]));
        *(uint4*)(Lb + TIER + awb + 16)  = make_uint4(PK(mm[8],mm[9]), PK(mm[10],mm[11]), PK(mm[12],mm[13]), PK(mm[14],mm[15]));
        *(uint4*)(Lb + 2*TIER + awb)     = make_uint4(PK(ll[0],ll[1]), PK(ll[2],ll[3]), PK(ll[4],ll[5]), PK(ll[6],ll[7]));
        *(uint4*)(Lb + 2*TIER + awb + 16)= make_uint4(PK(ll[8],ll[9]), PK(ll[10],ll[11]), PK(ll[12],ll[13]), PK(ll[14],ll[15]));
#undef PK
        {
            const uint4* p0 = (const uint4*)(WHb + k0);
            const uint4* p1 = (const uint4*)(WMb + k0);
            const uint4* p2 = (const uint4*)(WLb + k0);
            *(uint4*)(Lb + 3*TIER + awb)      = p0[0];
            *(uint4*)(Lb + 3*TIER + awb + 16) = p0[1];
            *(uint4*)(Lb + 4*TIER + awb)      = p1[0];
            *(uint4*)(Lb + 4*TIER + awb + 16) = p1[1];
            *(uint4*)(Lb + 5*TIER + awb)      = p2[0];
            *(uint4*)(Lb + 5*TIER + awb + 16) = p2[1];
        }
        __syncthreads();

        short8 ah[4], am4[4], al4[4], bh[4], bm4[4], bl4[4];
#pragma unroll
        for (int m = 0; m < 4; ++m) {
            ah[m]  = *(short8*)(Lb + aoff + m * 1280);
            am4[m] = *(short8*)(Lb + TIER + aoff + m * 1280);
            al4[m] = *(short8*)(Lb + 2 * TIER + aoff + m * 1280);
        }
#pragma unroll
        for (int n = 0; n < 4; ++n) {
            bh[n]  = *(short8*)(Lb + boff + n * 1280);
            bm4[n] = *(short8*)(Lb + TIER + boff + n * 1280);
            bl4[n] = *(short8*)(Lb + 2 * TIER + boff + n * 1280);
        }
#pragma unroll
        for (int m = 0; m < 4; ++m)
#pragma unroll
            for (int n = 0; n < 4; ++n) {
                f32x4 c = acc[m][n];
                c = __builtin_amdgcn_mfma_f32_16x16x32_bf16(al4[m], bh[n],  c, 0, 0, 0);
                c = __builtin_amdgcn_mfma_f32_16x16x32_bf16(ah[m],  bl4[n], c, 0, 0, 0);
                c = __builtin_amdgcn_mfma_f32_16x16x32_bf16(am4[m], bm4[n], c, 0, 0, 0);
                c = __builtin_amdgcn_mfma_f32_16x16x32_bf16(am4[m], bh[n],  c, 0, 0, 0);
                c = __builtin_amdgcn_mfma_f32_16x16x32_bf16(ah[m],  bm4[n], c, 0, 0, 0);
                c = __builtin_amdgcn_mfma_f32_16x16x32_bf16(ah[m],  bh[n],  c, 0, 0, 0);
                acc[m][n] = c;
            }
        __syncthreads();
    }

#pragma unroll
    for (int m = 0; m < 4; ++m)
#pragma unroll
        for (int n = 0; n < 4; ++n) {
            int cc = col0 + wn * 64 + n * 16 + fr;
            float b = bias[cc];
#pragma unroll
            for (int q = 0; q < 4; ++q) {
                int rr = row0 + wm * 64 + m * 16 + fg * 4 + q;
                C[(size_t)rr * N + cc] = acc[m][n][q] + b;
            }
        }
}

// ---------------------------------------------------------------------------
// fp32 tiled GEMM (GEMM1 K=50, GEMM4 N=100).
// ---------------------------------------------------------------------------
template <int BN_APPLY>
__global__ __launch_bounds__(256)
void gemm_k(const float* __restrict__ A, const float* __restrict__ W,
            const float* __restrict__ bias,
            const float* __restrict__ scale, const float* __restrict__ shift,
            float* __restrict__ C, int M, int K, int N)
{
    const int BM = 128, BN = 128, BK = 16;
    __shared__ __attribute__((aligned(16))) float As[BK][BM + 4];
    __shared__ __attribute__((aligned(16))) float Ws[BK][BN];
    int tid = threadIdx.x;
    int tm = tid >> 4, tn = tid & 15;
    int row0 = blockIdx.x * BM, col0 = blockIdx.y * BN;

    float acc[8][8];
#pragma unroll
    for (int i = 0; i < 8; ++i)
#pragma unroll
        for (int j = 0; j < 8; ++j) acc[i][j] = 0.f;

    int alr = tid >> 4;
    int alk = tid & 15;
    int wlc = tid & 127;
    int wlk = tid >> 7;

    for (int k0 = 0; k0 < K; k0 += BK) {
#pragma unroll
        for (int i = 0; i < 8; ++i) {
            int rr = row0 + alr + i * 16;
            int kk = k0 + alk;
            float v = 0.f;
            if (kk < K) {
                v = A[(size_t)rr * K + kk];
                if (BN_APPLY) v = fmaxf(v * scale[kk] + shift[kk], 0.f);
            }
            As[alk][alr + i * 16] = v;
        }
#pragma unroll
        for (int i = 0; i < 8; ++i) {
            int kk = k0 + wlk + i * 2;
            int cc = col0 + wlc;
            Ws[wlk + i * 2][wlc] = (kk < K && cc < N) ? W[(size_t)kk * N + cc] : 0.f;
        }
        __syncthreads();
#pragma unroll
        for (int kk = 0; kk < BK; ++kk) {
            float av[8], wv[8];
            float4 tv;
            tv = *(const float4*)&As[kk][tm * 8];     av[0]=tv.x; av[1]=tv.y; av[2]=tv.z; av[3]=tv.w;
            tv = *(const float4*)&As[kk][tm * 8 + 4]; av[4]=tv.x; av[5]=tv.y; av[6]=tv.z; av[7]=tv.w;
            tv = *(const float4*)&Ws[kk][tn * 8];     wv[0]=tv.x; wv[1]=tv.y; wv[2]=tv.z; wv[3]=tv.w;
            tv = *(const float4*)&Ws[kk][tn * 8 + 4]; wv[4]=tv.x; wv[5]=tv.y; wv[6]=tv.z; wv[7]=tv.w;
#pragma unroll
            for (int i = 0; i < 8; ++i)
#pragma unroll
                for (int j = 0; j < 8; ++j) acc[i][j] += av[i] * wv[j];
        }
        __syncthreads();
    }
#pragma unroll
    for (int i = 0; i < 8; ++i) {
        int rr = row0 + tm * 8 + i;
#pragma unroll
        for (int j = 0; j < 8; ++j) {
            int cc = col0 + tn * 8 + j;
            if (cc < N) C[(size_t)rr * N + cc] = acc[i][j] + bias[cc];
        }
    }
}

// ---------------------------------------------------------------------------
// BatchNorm stats.
// ---------------------------------------------------------------------------
__global__ __launch_bounds__(256)
void stats_part(const float* __restrict__ Z, float* __restrict__ ps,
                float* __restrict__ pq, int M, int C, int chunks)
{
    int lc = threadIdx.x & 63;
    int col = blockIdx.x * 64 + lc;
    int rg = threadIdx.x >> 6;
    int rpc = M / chunks;
    int r0 = blockIdx.y * rpc;
    float s = 0.f, q = 0.f;
    for (int rr = r0 + rg; rr < r0 + rpc; rr += 4) {
        float v = Z[(size_t)rr * C + col];
        s += v; q += v * v;
    }
    __shared__ float ls[4][64], lq[4][64];
    ls[rg][lc] = s; lq[rg][lc] = q;
    __syncthreads();
    if (rg == 0) {
        float S = ls[0][lc] + ls[1][lc] + ls[2][lc] + ls[3][lc];
        float Q = lq[0][lc] + lq[1][lc] + lq[2][lc] + lq[3][lc];
        ps[(size_t)blockIdx.y * C + col] = S;
        pq[(size_t)blockIdx.y * C + col] = Q;
    }
}

__global__ void stats_fin(const float* __restrict__ ps, const float* __restrict__ pq,
                          const float* __restrict__ g, const float* __restrict__ be,
                          float* __restrict__ scale, float* __restrict__ shift,
                          int C, int M, int chunks)
{
    int c = blockIdx.x * blockDim.x + threadIdx.x;
    if (c >= C) return;
    float S = 0.f, Q = 0.f;
    for (int i = 0; i < chunks; ++i) { S += ps[(size_t)i * C + c]; Q += pq[(size_t)i * C + c]; }
    float inv = 1.0f / (float)M;
    float mean = S * inv;
    float var = Q * inv - mean * mean;
    float rstd = 1.0f / sqrtf(var + EPSBN);
    float sc = g[c] * rstd;
    scale[c] = sc;
    shift[c] = be[c] - mean * sc;
}

// ---------------------------------------------------------------------------
// Fused 15-iteration ADMM, hybrid register/LDS split by dependency role:
//   rh[50]  : REGISTERS (only latency-critical stencil accumulator)
//   xi/xin  : double-buffered LDS [k][lane] (read/written once per pass,
//             sliding-window regs; compile-time offsets -> prefetchable)
//   lam, xv : LDS (off the critical path; xv loaded from XT once)
// One wave/block, lane-private columns -> barrier-free. Matvec: two register
// blocks of 25 independent accumulators (ascending-k order preserved).
// Peak live ~90 VGPR -> no scratch spill (the r4/r5 failure mode).
// ---------------------------------------------------------------------------
__global__ __launch_bounds__(64, 1)
void iter_k(const float* __restrict__ XT, const float* __restrict__ NNT,
            const float* __restrict__ MiT, float* __restrict__ out)
{
    __shared__ float sA[50 * 64];
    __shared__ float sB[50 * 64];
    __shared__ float sLam[50 * 64];
    __shared__ float sXv[50 * 64];
    const int lane = threadIdx.x;
    const int row = blockIdx.x * 64 + lane;
#define IDX(k) (((k) << 6) + lane)

#pragma unroll 1
    for (int k = 0; k < 50; ++k) {
        sA[IDX(k)]   = NNT[(size_t)k * BATCH + row];
        sLam[IDX(k)] = NNT[(size_t)(50 + k) * BATCH + row];
        sXv[IDX(k)]  = XT[(size_t)k * BATCH + row];
    }
    float* cx = sA;
    float* cn = sB;
    float fps = 0.f, prs = 0.f;
    float rh[50];

#pragma unroll 1
    for (int it = 0; it < 15; ++it) {
        // ---- pass 1: rh = A^T min(b, A xi); xi via sliding LDS reads
#pragma unroll
        for (int k = 0; k < 50; ++k) rh[k] = 0.f;
        {
            float pre = 0.f, Sp = 0.f, ap = 0.f;
            float xc = cx[IDX(0)];
#pragma unroll
            for (int k = 0; k < 50; ++k) {
                float xn = (k < 49) ? cx[IDX(k + 1)] : 0.f;
                rh[k] += fminf(VMAX, xc) - fminf(VMAX, -xc);
                rh[k] -= TF * Sp;
                pre += xc;
                float p = TF * pre;
                Sp += fminf(PMAX, p) - fminf(PMAX, -p);
                if (k < 49) {
                    float a = AF * (xn - xc);
                    float da = fminf(AMAX, a) - fminf(AMAX, -a);
                    rh[k] -= AF * da; rh[k + 1] += AF * da;
                    if (k >= 1) {
                        float j = AF * (a - ap);
                        float dj = fminf(JMAX, j) - fminf(JMAX, -j);
                        rh[k - 1] += JF * dj; rh[k] -= 2.f * JF * dj; rh[k + 1] += JF * dj;
                    }
                    ap = a;
                }
                xc = xn;
            }
            float Stot = TF * Sp;
#pragma unroll
            for (int k = 0; k < 50; ++k)
                rh[k] = rh[k] + sLam[IDX(k)] + sXv[IDX(k)] + Stot;
        }

        // ---- xin[j] = sum_k MiT[k][j]*rh[k]; two blocks of 25 indep accums
        {
            float xr[25];
#pragma unroll
            for (int j = 0; j < 25; ++j) xr[j] = 0.f;
#pragma unroll
            for (int k = 0; k < 50; ++k) {
                float rv = rh[k];
#pragma unroll
                for (int j = 0; j < 25; ++j) xr[j] += MiT[k * 50 + j] * rv;
            }
#pragma unroll
            for (int j = 0; j < 25; ++j) cn[IDX(j)] = xr[j];
        }
        {
            float xr[25];
#pragma unroll
            for (int j = 0; j < 25; ++j) xr[j] = 0.f;
#pragma unroll
            for (int k = 0; k < 50; ++k) {
                float rv = rh[k];
#pragma unroll
                for (int j = 0; j < 25; ++j) xr[j] += MiT[k * 50 + 25 + j] * rv;
            }
#pragma unroll
            for (int j = 0; j < 25; ++j) cn[IDX(25 + j)] = xr[j];
        }

        // ---- pass 2: residual/s norms + g (into rh); xi/xin sliding from LDS
        float res2 = 0.f, ds2 = 0.f, dxi2 = 0.f, dlam2 = 0.f;
#pragma unroll
        for (int k = 0; k < 50; ++k) rh[k] = 0.f;
        {
            float preo = 0.f, pren = 0.f, SpF = 0.f, aop = 0.f, anp = 0.f;
            float xoc = cx[IDX(0)], xnc = cn[IDX(0)];
#pragma unroll
            for (int k = 0; k < 50; ++k) {
                float xon = (k < 49) ? cx[IDX(k + 1)] : 0.f;
                float xnn = (k < 49) ? cn[IDX(k + 1)] : 0.f;
                float d = xoc - xnc; dxi2 += d * d;
                float rp = fmaxf(xnc - VMAX, 0.f), rm = fmaxf(-xnc - VMAX, 0.f);
                res2 += rp * rp + rm * rm;
                float so = fmaxf(VMAX - xoc, 0.f), sn = fmaxf(VMAX - xnc, 0.f);
                d = so - sn; ds2 += d * d;
                so = fmaxf(VMAX + xoc, 0.f); sn = fmaxf(VMAX + xnc, 0.f);
                d = so - sn; ds2 += d * d;
                rh[k] += rp - rm;
                rh[k] -= TF * SpF;
                preo += xoc; pren += xnc;
                float po = TF * preo, pn = TF * pren;
                rp = fmaxf(pn - PMAX, 0.f); rm = fmaxf(-pn - PMAX, 0.f);
                res2 += rp * rp + rm * rm;
                so = fmaxf(PMAX - po, 0.f); sn = fmaxf(PMAX - pn, 0.f);
                d = so - sn; ds2 += d * d;
                so = fmaxf(PMAX + po, 0.f); sn = fmaxf(PMAX + pn, 0.f);
                d = so - sn; ds2 += d * d;
                SpF += rp - rm;
                if (k < 49) {
                    float ao = AF * (xon - xoc), an = AF * (xnn - xnc);
                    rp = fmaxf(an - AMAX, 0.f); rm = fmaxf(-an - AMAX, 0.f);
                    res2 += rp * rp + rm * rm;
                    so = fmaxf(AMAX - ao, 0.f); sn = fmaxf(AMAX - an, 0.f);
                    d = so - sn; ds2 += d * d;
                    so = fmaxf(AMAX + ao, 0.f); sn = fmaxf(AMAX + an, 0.f);
                    d = so - sn; ds2 += d * d;
                    float fa = rp - rm; rh[k] -= AF * fa; rh[k + 1] += AF * fa;
                    if (k >= 1) {
                        float jo = AF * (ao - aop), jn = AF * (an - anp);
                        rp = fmaxf(jn - JMAX, 0.f); rm = fmaxf(-jn - JMAX, 0.f);
                        res2 += rp * rp + rm * rm;
                        so = fmaxf(JMAX - jo, 0.f); sn = fmaxf(JMAX - jn, 0.f);
                        d = so - sn; ds2 += d * d;
                        so = fmaxf(JMAX + jo, 0.f); sn = fmaxf(JMAX + jn, 0.f);
                        d = so - sn; ds2 += d * d;
                        float fj = rp - rm;
                        rh[k - 1] += JF * fj; rh[k] -= 2.f * JF * fj; rh[k + 1] += JF * fj;
                    }
                    aop = ao; anp = an;
                }
                xoc = xon; xnc = xnn;
            }
            float SF = TF * SpF;
#pragma unroll
            for (int k = 0; k < 50; ++k) {
                float gk = rh[k] + SF;
                dlam2 += gk * gk;
                sLam[IDX(k)] -= gk;
            }
        }
        prs += sqrtf(res2);
        fps += sqrtf(dxi2) + sqrtf(dlam2) + sqrtf(ds2);
        float* tp = cx; cx = cn; cn = tp;
    }
#pragma unroll 1
    for (int k = 0; k < 50; ++k) out[(size_t)row * 50 + k] = cx[IDX(k)];
    out[(size_t)BATCH * 50 + row] = fps * (1.f / 15.f);
    out[(size_t)BATCH * 51 + row] = prs * (1.f / 15.f);
#undef IDX
}

// ---------------------------------------------------------------------------
extern "C" void kernel_launch(void* const* d_in, const int* in_sizes, int n_in,
                              void* d_out, int out_size, void* d_ws, size_t ws_size,
                              hipStream_t stream)
{
    const float* x   = (const float*)d_in[0];
    const float* W1  = (const float*)d_in[1];
    const float* b1  = (const float*)d_in[2];
    const float* g1  = (const float*)d_in[3];
    const float* be1 = (const float*)d_in[4];
    const float* W2  = (const float*)d_in[5];
    const float* b2  = (const float*)d_in[6];
    const float* g2  = (const float*)d_in[7];
    const float* be2 = (const float*)d_in[8];
    const float* W3  = (const float*)d_in[9];
    const float* b3  = (const float*)d_in[10];
    const float* g3  = (const float*)d_in[11];
    const float* be3 = (const float*)d_in[12];
    const float* W4  = (const float*)d_in[13];
    const float* b4  = (const float*)d_in[14];

    float *z1, *z2, *ps, *pq, *scb, *shb, *Mi, *xT, *nnT;
    ushort_t *w2h, *w2m, *w2l, *w3h, *w3m, *w3l;
    hipGetSymbolAddress((void**)&z1,  HIP_SYMBOL(g_z1));
    hipGetSymbolAddress((void**)&z2,  HIP_SYMBOL(g_z2));
    hipGetSymbolAddress((void**)&ps,  HIP_SYMBOL(g_ps));
    hipGetSymbolAddress((void**)&pq,  HIP_SYMBOL(g_pq));
    hipGetSymbolAddress((void**)&scb, HIP_SYMBOL(g_scale));
    hipGetSymbolAddress((void**)&shb, HIP_SYMBOL(g_shift));
    hipGetSymbolAddress((void**)&Mi,  HIP_SYMBOL(g_Mi));
    hipGetSymbolAddress((void**)&xT,  HIP_SYMBOL(g_xT));
    hipGetSymbolAddress((void**)&nnT, HIP_SYMBOL(g_nnT));
    hipGetSymbolAddress((void**)&w2h, HIP_SYMBOL(g_w2h));
    hipGetSymbolAddress((void**)&w2m, HIP_SYMBOL(g_w2m));
    hipGetSymbolAddress((void**)&w2l, HIP_SYMBOL(g_w2l));
    hipGetSymbolAddress((void**)&w3h, HIP_SYMBOL(g_w3h));
    hipGetSymbolAddress((void**)&w3m, HIP_SYMBOL(g_w3m));
    hipGetSymbolAddress((void**)&w3l, HIP_SYMBOL(g_w3l));

    float* z3  = z1;                        // z1 dead after GEMM2
    float* nno = z1 + (size_t)BATCH * H3;   // after z3
    float* sc1 = scb;        float* sh1 = shb;
    float* sc2 = scb + 1024; float* sh2 = shb + 1024;
    float* sc3 = scb + 2048; float* sh3 = shb + 2048;

    dim3 blk(256);
    hipLaunchKernelGGL(build_M, dim3(1), dim3(64), 0, stream, Mi);
    hipLaunchKernelGGL(wsplit, dim3(H2 / 32, H1 / 32), blk, 0, stream, W2, w2h, w2m, w2l, H1, H2);
    hipLaunchKernelGGL(wsplit, dim3(H3 / 32, H2 / 32), blk, 0, stream, W3, w3h, w3m, w3l, H2, H3);
    hipLaunchKernelGGL((transp<50>), dim3(BATCH / 64), dim3(64), 0, stream, x, xT);

    // L1: z1 = x @ W1 + b1 (fp32 vector path, K=50)
    hipLaunchKernelGGL((gemm_k<0>), dim3(BATCH / 128, H1 / 128), blk, 0, stream,
                       x, W1, b1, (const float*)nullptr, (const float*)nullptr,
                       z1, BATCH, NVARS, H1);
    hipLaunchKernelGGL(stats_part, dim3(H1 / 64, 32), blk, 0, stream, z1, ps, pq, BATCH, H1, 32);
    hipLaunchKernelGGL(stats_fin, dim3(4), dim3(256), 0, stream, ps, pq, g1, be1, sc1, sh1, H1, BATCH, 32);
    // L2: z2 = relu(bn(z1)) @ W2 + b2 (MFMA split)
    hipLaunchKernelGGL((gemm_mfma<1>), dim3(BATCH / 128, H2 / 128), blk, 0, stream,
                       z1, w2h, w2m, w2l, b2, sc1, sh1, z2, BATCH, H1, H2);
    hipLaunchKernelGGL(stats_part, dim3(H2 / 64, 32), blk, 0, stream, z2, ps, pq, BATCH, H2, 32);
    hipLaunchKernelGGL(stats_fin, dim3(4), dim3(256), 0, stream, ps, pq, g2, be2, sc2, sh2, H2, BATCH, 32);
    // L3: z3 = relu(bn(z2)) @ W3 + b3 (MFMA split)
    hipLaunchKernelGGL((gemm_mfma<1>), dim3(BATCH / 128, H3 / 128), blk, 0, stream,
                       z2, w3h, w3m, w3l, b3, sc2, sh2, z3, BATCH, H2, H3);
    hipLaunchKernelGGL(stats_part, dim3(H3 / 64, 32), blk, 0, stream, z3, ps, pq, BATCH, H3, 32);
    hipLaunchKernelGGL(stats_fin, dim3(1), dim3(256), 0, stream, ps, pq, g3, be3, sc3, sh3, H3, BATCH, 32);
    // L4: nno = relu(bn(z3)) @ W4 + b4 (fp32 vector path, N=100)
    hipLaunchKernelGGL((gemm_k<1>), dim3(BATCH / 128, 1), blk, 0, stream,
                       z3, W4, b4, sc3, sh3, nno, BATCH, H3, NOUT);
    hipLaunchKernelGGL((transp<100>), dim3(BATCH / 64), dim3(64), 0, stream, nno, nnT);
    // fused ADMM iterations (hybrid reg/LDS, barrier-free)
    hipLaunchKernelGGL(iter_k, dim3(BATCH / 64), dim3(64), 0, stream,
                       xT, nnT, Mi, (float*)d_out);
}